// Round 5
// baseline (388.490 us; speedup 1.0000x reference)
//
#include <hip/hip_runtime.h>

#define DEV static __device__ __forceinline__

using bf16x8 = __attribute__((ext_vector_type(8))) short;
using f32x4  = __attribute__((ext_vector_type(4))) float;
using f32x16 = __attribute__((ext_vector_type(16))) float;
using bfp2   = __attribute__((ext_vector_type(2))) __bf16;
using u32x2  = __attribute__((ext_vector_type(2))) unsigned;

DEV unsigned short f2bf(float f){
  return __builtin_bit_cast(unsigned short, (__bf16)f);
}
DEV unsigned pk2(float a, float b){
  bfp2 v = {(__bf16)a, (__bf16)b};
  return __builtin_bit_cast(unsigned, v);
}
DEV void wr64(void* p, float a, float b, float c, float d){
  u32x2 v = {pk2(a, b), pk2(c, d)};
  *(u32x2*)p = v;
}

// gelu(x) = x*Phi(x); Phi via odd deg-9 polynomial, |x|<=1.3, err ~1e-5.
DEV float gelu_f(float x){
  float u = x * x;
  float c = __builtin_fmaf(u, 1.1543811e-4f, -1.1872348e-3f);
  c = __builtin_fmaf(u, c,  9.9735570e-3f);
  c = __builtin_fmaf(u, c, -6.6490380e-2f);
  c = __builtin_fmaf(u, c,  3.9894228e-1f);
  float t = __builtin_fmaf(x, c, 0.5f);
  return x * t;
}

// ---------------------------------------------------------------------------
// ws layout: bf16 Wh[4096] Wp[4096] W1[8192] W2[8192] Wo[4096]  (57344 B)
//            then f32 RBf[16384] @ byte 57344 (rel_bias, log2e-scaled, D-layout)
// W packed as MFMA frags: idx = ((kb*NB+nb)*64 + lane)*8 + e,
//   value = W[kb*32 + (lane>>4)*8 + e][nb*16 + (lane&15)]
// RBf in 32x32 D-reg order: idx = ((h*4+qt)*64 + lane)*16 + reg,
//   value = log2e * rel_bias[h][qt*32 + (lane&31)][(reg&3) + 8*(reg>>2) + 4*(lane>>5)]
// ---------------------------------------------------------------------------
__global__ void pack_weights(const float* __restrict__ Wh, const float* __restrict__ Wp,
                             const float* __restrict__ W1, const float* __restrict__ W2,
                             const float* __restrict__ Wo, const float* __restrict__ RB,
                             unsigned short* __restrict__ ws)
{
  const int gid = blockIdx.x * 256 + threadIdx.x;
  const float* W; unsigned short* o; int N, NB, idx;
  if      (gid < 4096)  { W = Wh; o = ws;         N = 64;  NB = 4; idx = gid;         }
  else if (gid < 8192)  { W = Wp; o = ws + 4096;  N = 64;  NB = 4; idx = gid - 4096;  }
  else if (gid < 16384) { W = W1; o = ws + 8192;  N = 128; NB = 8; idx = gid - 8192;  }
  else if (gid < 24576) { W = W2; o = ws + 16384; N = 64;  NB = 4; idx = gid - 16384; }
  else if (gid < 28672) { W = Wo; o = ws + 24576; N = 64;  NB = 4; idx = gid - 24576; }
  else {
    const int idx2 = gid - 28672;                 // < 16384
    const int r = idx2 & 15, lx = (idx2 >> 4) & 63, fid = idx2 >> 10;
    const int qt = fid & 3, h = fid >> 2;
    const int q  = qt * 32 + (lx & 31);
    const int kp = (r & 3) + 8 * (r >> 2) + 4 * (lx >> 5);
    ((float*)(ws + 28672))[idx2] = 1.44269504f * RB[((size_t)h * 128 + q) * 128 + kp];
    return;
  }
  const int e = idx & 7, lx = (idx >> 3) & 63, fid = idx >> 9;
  const int kb = fid / NB, nb = fid % NB;
  const int k  = kb * 32 + ((lx >> 4) & 3) * 8 + e;
  const int n  = nb * 16 + (lx & 15);
  o[idx] = f2bf(W[k * N + n]);
}

// ---------------------------------------------------------------------------
// Fused kernel, transposed-world MFMAs. 1 block (4 waves)/batch item.
// LDS (25600 B -> 6 blocks/CU), all XOR-swizzled 128B-stride rows:
//   kv  @0    : 32 tok rows * 128B  [token][64 feat], slot^=(row&7)
//   kvT @4096 : 64 feat rows * 80B  [feat][32 tok], unswizzled
//   QX(w) @9216+w*4096 : 32 rows * 128B, slot^=(row&7).
//     Holds Q (scaled); P(h) overlays logical slots 0-3 (Q heads 0,1 dead
//     after qB0/qB1 consumed -> qB1 hoisted); then X, T, resid.
// Swizzle: addr = base + row*128 + (((byte>>4) ^ (row&7))<<4) + (byte&15)
// ---------------------------------------------------------------------------
#define KV_OFF  0u
#define KVT_OFF 4096u
#define QX_BASE 9216u
#define SC_Q 0.36067376f   // 0.25 * log2(e)

DEV unsigned qoff(unsigned base, unsigned row, unsigned byte){
  return base + row * 128u + ((((byte >> 4) ^ (row & 7u)) & 7u) << 4) + (byte & 15u);
}

__global__ __launch_bounds__(256, 6)
void fused_kernel(const float* __restrict__ hla_in, const float* __restrict__ pep_in,
                  const float* __restrict__ bhla_p, const float* __restrict__ bpep_p,
                  const float* __restrict__ lng_p,  const float* __restrict__ lnb_p,
                  const float* __restrict__ b1_p,   const float* __restrict__ b2_p,
                  const float* __restrict__ bout_p,
                  const unsigned short* __restrict__ pk,
                  float* __restrict__ out)
{
  __shared__ __align__(16) unsigned char lds[25600];
  const int b   = blockIdx.x;
  const int tid = threadIdx.x;
  const int w   = tid >> 6;
  const int l   = tid & 63;
  const int li  = l & 15, l4 = l >> 4;
  const int lq  = l & 31, l5 = l >> 5;
  const int R0  = 32 * w;
  const unsigned QX = QX_BASE + (unsigned)w * 4096u;

  const unsigned short* pWh = pk;
  const unsigned short* pWp = pk + 4096;
  const unsigned short* pW1 = pk + 8192;
  const unsigned short* pW2 = pk + 16384;
  const unsigned short* pWo = pk + 24576;
  const float* pRBf = (const float*)(pk + 28672);

  // ---- P0a: pep projection -> kv [tok][feat] (swz), kvT [feat][tok] -------
  {
    const int mt = w & 1, np = w >> 1;
    bf16x8 xP[2];
#pragma unroll
    for (int kb = 0; kb < 2; ++kb){
      const float* s = pep_in + ((size_t)b * 32 + 16 * mt + li) * 64 + kb * 32 + l4 * 8;
      f32x4 u0 = *(const f32x4*)s;
      f32x4 u1 = *(const f32x4*)(s + 4);
      bf16x8 a;
      a[0] = (short)f2bf(u0[0]); a[1] = (short)f2bf(u0[1]);
      a[2] = (short)f2bf(u0[2]); a[3] = (short)f2bf(u0[3]);
      a[4] = (short)f2bf(u1[0]); a[5] = (short)f2bf(u1[1]);
      a[6] = (short)f2bf(u1[2]); a[7] = (short)f2bf(u1[3]);
      xP[kb] = a;
    }
#pragma unroll
    for (int t = 0; t < 2; ++t){
      const int nt = 2 * np + t;
      f32x4 acc = *(const f32x4*)(bpep_p + nt * 16 + l4 * 4);   // bias as C-init
#pragma unroll
      for (int kb = 0; kb < 2; ++kb){
        bf16x8 wf = *(const bf16x8*)(pWp + (size_t)((kb * 4 + nt) * 64 + l) * 8);
        acc = __builtin_amdgcn_mfma_f32_16x16x32_bf16(wf, xP[kb], acc, 0, 0, 0);
      }
      // D: feature nt*16+l4*4+r, token 16mt+li
      wr64(lds + qoff(KV_OFF, 16 * mt + li, 32 * nt + 8 * l4),
           acc[0], acc[1], acc[2], acc[3]);
#pragma unroll
      for (int r = 0; r < 4; ++r)
        *(unsigned short*)(lds + KVT_OFF + (nt * 16 + l4 * 4 + r) * 80 + (16 * mt + li) * 2)
            = f2bf(acc[r]);
    }
  }

  // ---- P0b: hla projection -> acc4 (f32 regs) + Q (scaled bf16, swz) ------
  f32x4 acc4[2][4];   // [token-half ms][feat-16-block nt], reg r = feat l4*4+r
  {
    bf16x8 xH[2][2];
#pragma unroll
    for (int ms = 0; ms < 2; ++ms)
#pragma unroll
    for (int kb = 0; kb < 2; ++kb){
      const float* s = hla_in + ((size_t)b * 128 + R0 + ms * 16 + li) * 64 + kb * 32 + l4 * 8;
      f32x4 u0 = *(const f32x4*)s;
      f32x4 u1 = *(const f32x4*)(s + 4);
      bf16x8 a;
      a[0] = (short)f2bf(u0[0]); a[1] = (short)f2bf(u0[1]);
      a[2] = (short)f2bf(u0[2]); a[3] = (short)f2bf(u0[3]);
      a[4] = (short)f2bf(u1[0]); a[5] = (short)f2bf(u1[1]);
      a[6] = (short)f2bf(u1[2]); a[7] = (short)f2bf(u1[3]);
      xH[ms][kb] = a;
    }
#pragma unroll
    for (int nt = 0; nt < 4; ++nt){
      f32x4 cin = *(const f32x4*)(bhla_p + nt * 16 + l4 * 4);
      f32x4 a0 = cin, a1 = cin;
#pragma unroll
      for (int kb = 0; kb < 2; ++kb){
        bf16x8 wf = *(const bf16x8*)(pWh + (size_t)((kb * 4 + nt) * 64 + l) * 8);
        a0 = __builtin_amdgcn_mfma_f32_16x16x32_bf16(wf, xH[0][kb], a0, 0, 0, 0);
        a1 = __builtin_amdgcn_mfma_f32_16x16x32_bf16(wf, xH[1][kb], a1, 0, 0, 0);
      }
      acc4[0][nt] = a0;
      acc4[1][nt] = a1;
      wr64(lds + qoff(QX, li, 32 * nt + 8 * l4),
           a0[0] * SC_Q, a0[1] * SC_Q, a0[2] * SC_Q, a0[3] * SC_Q);
      wr64(lds + qoff(QX, 16 + li, 32 * nt + 8 * l4),
           a1[0] * SC_Q, a1[1] * SC_Q, a1[2] * SC_Q, a1[3] * SC_Q);
    }
  }

  __syncthreads();   // kv/kvT ready (only barrier)

  // ---- P1: scores = mfma(kv, Qs, C=RBf), exp2 softmax; P overlays Q[0:2] --
  f32x4 ctxacc[2][4];   // [ms][h]: feat h*16+l4*4+r, token ms*16+li
#pragma unroll
  for (int ms = 0; ms < 2; ++ms)
#pragma unroll
  for (int h = 0; h < 4; ++h){
    f32x4 z = {0.f, 0.f, 0.f, 0.f};
    ctxacc[ms][h] = z;
  }

  // hoist qB(1): its Q slots get overwritten by P(0)
  bf16x8 qB1 = *(const bf16x8*)(lds + qoff(QX, lq, 32 + 16 * l5));

#pragma unroll
  for (int h = 0; h < 4; ++h){
    bf16x8 kvA = *(const bf16x8*)(lds + qoff(KV_OFF, lq, 32 * h + 16 * l5));
    bf16x8 qB  = (h == 1) ? qB1
               : *(const bf16x8*)(lds + qoff(QX, lq, 32 * h + 16 * l5));
    const f32x4* rp = (const f32x4*)(pRBf + (size_t)((h * 4 + w) * 64 + l) * 16);
    f32x4 c0 = rp[0], c1 = rp[1], c2 = rp[2], c3 = rp[3];
    f32x16 cc;
#pragma unroll
    for (int i = 0; i < 4; ++i){
      cc[i] = c0[i]; cc[4 + i] = c1[i]; cc[8 + i] = c2[i]; cc[12 + i] = c3[i];
    }
    f32x16 sc = __builtin_amdgcn_mfma_f32_32x32x16_bf16(kvA, qB, cc, 0, 0, 0);

    float p[16], sum = 0.f;
#pragma unroll
    for (int i = 0; i < 16; ++i){ p[i] = __builtin_amdgcn_exp2f(sc[i]); sum += p[i]; }
    sum += __shfl_xor(sum, 32);
    const float rs = __builtin_amdgcn_rcpf(sum);

#pragma unroll
    for (int qd = 0; qd < 4; ++qd)
      wr64(lds + qoff(QX, lq, 16 * qd + 8 * l5),
           p[4 * qd] * rs, p[4 * qd + 1] * rs, p[4 * qd + 2] * rs, p[4 * qd + 3] * rs);
    asm volatile("" ::: "memory");

    bf16x8 aV = *(const bf16x8*)(lds + KVT_OFF + (h * 16 + li) * 80 + l4 * 16);
#pragma unroll
    for (int ms = 0; ms < 2; ++ms){
      bf16x8 bP = *(const bf16x8*)(lds + qoff(QX, ms * 16 + li, l4 * 16));
      ctxacc[ms][h] = __builtin_amdgcn_mfma_f32_16x16x32_bf16(aV, bP, ctxacc[ms][h], 0, 0, 0);
    }
    asm volatile("" ::: "memory");
  }

  // ---- P2: LayerNorm over features (in-lane 16 + shfl 16/32) -> X ---------
  f32x4 gv[4], bv[4];
#pragma unroll
  for (int h = 0; h < 4; ++h){
    gv[h] = *(const f32x4*)(lng_p + h * 16 + l4 * 4);
    bv[h] = *(const f32x4*)(lnb_p + h * 16 + l4 * 4);
  }
#pragma unroll
  for (int ms = 0; ms < 2; ++ms){
    f32x4 s4 = ctxacc[ms][0] + ctxacc[ms][1] + ctxacc[ms][2] + ctxacc[ms][3];
    float s = s4[0] + s4[1] + s4[2] + s4[3];
    s += __shfl_xor(s, 16);
    s += __shfl_xor(s, 32);
    const float mean = s * 0.015625f;
    float q = 0.f;
#pragma unroll
    for (int h = 0; h < 4; ++h)
#pragma unroll
    for (int r = 0; r < 4; ++r) q = __builtin_fmaf(ctxacc[ms][h][r], ctxacc[ms][h][r], q);
    q += __shfl_xor(q, 16);
    q += __shfl_xor(q, 32);
    const float var  = __builtin_fmaf(mean, -mean, q * 0.015625f);
    const float rstd = __builtin_amdgcn_rsqf(var + 1e-5f);
#pragma unroll
    for (int h = 0; h < 4; ++h){
      f32x4 y;
#pragma unroll
      for (int r = 0; r < 4; ++r)
        y[r] = __builtin_fmaf((ctxacc[ms][h][r] - mean) * rstd, gv[h][r], bv[h][r]);
      wr64(lds + qoff(QX, ms * 16 + li, 32 * h + 8 * l4), y[0], y[1], y[2], y[3]);
    }
  }
  asm volatile("" ::: "memory");

  // ---- P3: FFN; X in regs, T reuses QX region; acc4 accumulates W2 --------
  bf16x8 xF[2][2];
#pragma unroll
  for (int ms = 0; ms < 2; ++ms)
#pragma unroll
  for (int kb = 0; kb < 2; ++kb)
    xF[ms][kb] = *(const bf16x8*)(lds + qoff(QX, ms * 16 + li, 64 * kb + 16 * l4));
  asm volatile("" ::: "memory");

#pragma unroll
  for (int half = 0; half < 2; ++half){
#pragma unroll
    for (int nt = 0; nt < 4; ++nt){
      f32x4 cin = *(const f32x4*)(b1_p + half * 64 + nt * 16 + l4 * 4);
      f32x4 h0 = cin, h1 = cin;
#pragma unroll
      for (int kb = 0; kb < 2; ++kb){
        bf16x8 wf = *(const bf16x8*)(pW1 + (size_t)((kb * 8 + half * 4 + nt) * 64 + l) * 8);
        h0 = __builtin_amdgcn_mfma_f32_16x16x32_bf16(wf, xF[0][kb], h0, 0, 0, 0);
        h1 = __builtin_amdgcn_mfma_f32_16x16x32_bf16(wf, xF[1][kb], h1, 0, 0, 0);
      }
      wr64(lds + qoff(QX, li, 32 * nt + 8 * l4),
           gelu_f(h0[0]), gelu_f(h0[1]), gelu_f(h0[2]), gelu_f(h0[3]));
      wr64(lds + qoff(QX, 16 + li, 32 * nt + 8 * l4),
           gelu_f(h1[0]), gelu_f(h1[1]), gelu_f(h1[2]), gelu_f(h1[3]));
    }
    asm volatile("" ::: "memory");
    bf16x8 tF[2][2];
#pragma unroll
    for (int ms = 0; ms < 2; ++ms)
#pragma unroll
    for (int kb = 0; kb < 2; ++kb)
      tF[ms][kb] = *(const bf16x8*)(lds + qoff(QX, ms * 16 + li, 64 * kb + 16 * l4));
#pragma unroll
    for (int nt = 0; nt < 4; ++nt){
#pragma unroll
      for (int kb = 0; kb < 2; ++kb){
        bf16x8 wf = *(const bf16x8*)(pW2 + (size_t)(((half * 2 + kb) * 4 + nt) * 64 + l) * 8);
        acc4[0][nt] = __builtin_amdgcn_mfma_f32_16x16x32_bf16(wf, tF[0][kb], acc4[0][nt], 0, 0, 0);
        acc4[1][nt] = __builtin_amdgcn_mfma_f32_16x16x32_bf16(wf, tF[1][kb], acc4[1][nt], 0, 0, 0);
      }
    }
    asm volatile("" ::: "memory");
  }

  // ---- residual: hla2pep = acc4 + b2 -> bf16 in QX ------------------------
#pragma unroll
  for (int nt = 0; nt < 4; ++nt){
    f32x4 b2v = *(const f32x4*)(b2_p + nt * 16 + l4 * 4);
#pragma unroll
    for (int ms = 0; ms < 2; ++ms){
      f32x4 v = acc4[ms][nt] + b2v;
      wr64(lds + qoff(QX, ms * 16 + li, 32 * nt + 8 * l4), v[0], v[1], v[2], v[3]);
    }
  }
  asm volatile("" ::: "memory");

  // ---- P4: output projection; stores are dwordx4 --------------------------
  bf16x8 rF[2][2];
#pragma unroll
  for (int ms = 0; ms < 2; ++ms)
#pragma unroll
  for (int kb = 0; kb < 2; ++kb)
    rF[ms][kb] = *(const bf16x8*)(lds + qoff(QX, ms * 16 + li, 64 * kb + 16 * l4));

#pragma unroll
  for (int nt = 0; nt < 4; ++nt){
    f32x4 cin = *(const f32x4*)(bout_p + nt * 16 + l4 * 4);
    f32x4 o0 = cin, o1 = cin;
#pragma unroll
    for (int kb = 0; kb < 2; ++kb){
      bf16x8 wf = *(const bf16x8*)(pWo + (size_t)((kb * 4 + nt) * 64 + l) * 8);
      o0 = __builtin_amdgcn_mfma_f32_16x16x32_bf16(wf, rF[0][kb], o0, 0, 0, 0);
      o1 = __builtin_amdgcn_mfma_f32_16x16x32_bf16(wf, rF[1][kb], o1, 0, 0, 0);
    }
    *(f32x4*)(out + ((size_t)b * 128 + R0 + li) * 64 + nt * 16 + l4 * 4)      = o0;
    *(f32x4*)(out + ((size_t)b * 128 + R0 + 16 + li) * 64 + nt * 16 + l4 * 4) = o1;
  }
}

extern "C" void kernel_launch(void* const* d_in, const int* in_sizes, int n_in,
                              void* d_out, int out_size, void* d_ws, size_t ws_size,
                              hipStream_t stream)
{
  const float* hla  = (const float*)d_in[0];
  const float* pep  = (const float*)d_in[1];
  const float* Wh   = (const float*)d_in[2];
  const float* bhla = (const float*)d_in[3];
  const float* Wp   = (const float*)d_in[4];
  const float* bpep = (const float*)d_in[5];
  const float* RB   = (const float*)d_in[6];
  const float* lng  = (const float*)d_in[7];
  const float* lnb  = (const float*)d_in[8];
  const float* W1   = (const float*)d_in[9];
  const float* b1   = (const float*)d_in[10];
  const float* W2   = (const float*)d_in[11];
  const float* b2   = (const float*)d_in[12];
  const float* Wo   = (const float*)d_in[13];
  const float* bo   = (const float*)d_in[14];
  unsigned short* ws = (unsigned short*)d_ws;
  float* outp = (float*)d_out;

  hipLaunchKernelGGL(pack_weights, dim3(176), dim3(256), 0, stream,
                     Wh, Wp, W1, W2, Wo, RB, ws);
  hipLaunchKernelGGL(fused_kernel, dim3(4096), dim3(256), 0, stream,
                     hla, pep, bhla, bpep, lng, lnb, b1, b2, bo, ws, outp);
}